// Round 13
// baseline (326.983 us; speedup 1.0000x reference)
//
#include <hip/hip_runtime.h>
#include <hip/hip_fp16.h>
#include <math.h>

#define NG 1024      // NUM_GRAPHS
#define EPB 2048     // edges per bucket_count block
#define EPB_BIN 4096 // edges per bin_edges block (LDS-staged)

static inline int cdiv_i(long long a, int b) { return (int)((a + b - 1) / b); }

// ---- fp16 pack/unpack helpers (8 halves per uint4) -----------------------
union H8 { uint4 u; __half2 h[4]; };

__device__ inline void h8_to_f(uint4 uu, float* f) {
    H8 v; v.u = uu;
#pragma unroll
    for (int k = 0; k < 4; ++k) {
        float2 t = __half22float2(v.h[k]);
        f[2 * k] = t.x; f[2 * k + 1] = t.y;
    }
}
__device__ inline uint4 f_to_h8(const float* f) {
    H8 v;
#pragma unroll
    for (int k = 0; k < 4; ++k) v.h[k] = __floats2half2_rn(f[2 * k], f[2 * k + 1]);
    return v.u;
}

// ---- init: zero bcnt (256) + pooled (NG*64) in one dispatch --------------
__global__ void zero_init(int* __restrict__ bcnt, unsigned* __restrict__ pooled) {
    int t = blockIdx.x * 256 + threadIdx.x;
    if (t < 256) bcnt[t] = 0;
    if (t < NG * 64) pooled[t] = 0;
}

// ---- CSR build (bucketed) ------------------------------------------------
// bucket b = nodes [b*512, (b+1)*512)

__global__ void bucket_count(const int* __restrict__ dst, int* __restrict__ bcnt, int E) {
    __shared__ int h[256];
    int t = threadIdx.x;
    h[t] = 0;
    __syncthreads();
    int e0 = blockIdx.x * EPB;
#pragma unroll 4
    for (int k = 0; k < EPB / 256; ++k) {
        int e = e0 + k * 256 + t;
        if (e < E) atomicAdd(&h[dst[e] >> 9], 1);
    }
    __syncthreads();
    if (h[t] > 0) atomicAdd(&bcnt[t], h[t]);
}

__global__ void bucket_scan(const int* __restrict__ bcnt, int* __restrict__ bktbase,
                            int* __restrict__ bktcur, int* __restrict__ rowptr,
                            int NBKT, int N) {
    __shared__ int s[256];
    int t = threadIdx.x;
    int v = (t < NBKT) ? bcnt[t] : 0;
    s[t] = v;
    __syncthreads();
    for (int off = 1; off < 256; off <<= 1) {
        int u = (t >= off) ? s[t - off] : 0;
        __syncthreads();
        s[t] += u;
        __syncthreads();
    }
    int excl = s[t] - v;
    if (t < NBKT) { bktbase[t] = excl; bktcur[t] = excl; }
    if (t == 255) { bktbase[NBKT] = s[255]; rowptr[N] = s[255]; }
}

// bin edges bucket-major via LDS counting sort; packed = (dst&511)<<23 | src.
__global__ void bin_edges(const int* __restrict__ src, const int* __restrict__ dst,
                          int* __restrict__ bktcur, unsigned* __restrict__ binned, int E) {
    __shared__ int hist[256];
    __shared__ int sc[256];
    __shared__ int lofs[256];
    __shared__ int gbase[256];
    __shared__ int lcur[256];
    __shared__ unsigned stage[EPB_BIN];
    __shared__ int gaddr[EPB_BIN];
    int t = threadIdx.x;
    hist[t] = 0;
    __syncthreads();
    int e0 = blockIdx.x * EPB_BIN;
    int ne = E - e0; if (ne > EPB_BIN) ne = EPB_BIN;
    int myd[EPB_BIN / 256];
    int mys[EPB_BIN / 256];
#pragma unroll
    for (int k = 0; k < EPB_BIN / 256; ++k) {
        int e = e0 + k * 256 + t;
        if (e < E) {
            int d = dst[e];
            myd[k] = d;
            atomicAdd(&hist[d >> 9], 1);
        } else {
            myd[k] = -1;
        }
    }
#pragma unroll
    for (int k = 0; k < EPB_BIN / 256; ++k) {
        int e = e0 + k * 256 + t;
        mys[k] = (e < E) ? src[e] : 0;
    }
    __syncthreads();
    int v = hist[t];
    sc[t] = v;
    __syncthreads();
    for (int off = 1; off < 256; off <<= 1) {
        int u = (t >= off) ? sc[t - off] : 0;
        __syncthreads();
        sc[t] += u;
        __syncthreads();
    }
    lofs[t] = sc[t] - v;
    lcur[t] = sc[t] - v;
    if (v > 0) gbase[t] = atomicAdd(&bktcur[t], v);
    __syncthreads();
#pragma unroll
    for (int k = 0; k < EPB_BIN / 256; ++k) {
        int d = myd[k];
        if (d >= 0) {
            int b = d >> 9;
            int r = atomicAdd(&lcur[b], 1);
            stage[r] = ((unsigned)(d & 511) << 23) | (unsigned)mys[k];
            gaddr[r] = gbase[b] + (r - lofs[b]);
        }
    }
    __syncthreads();
    for (int j = t; j < ne; j += 256) binned[gaddr[j]] = stage[j];
}

__global__ void bucket_build(const int* __restrict__ bktbase, const unsigned* __restrict__ binned,
                             int* __restrict__ rowptr, float* __restrict__ dinv,
                             int* __restrict__ csr_src, int N) {
    __shared__ int degl[512];
    __shared__ int s[512];
    __shared__ int rp[512];
    __shared__ int cur[512];
    int t = threadIdx.x;  // 512
    int n0 = blockIdx.x << 9;
    degl[t] = 0;
    cur[t] = 0;
    __syncthreads();
    int base = bktbase[blockIdx.x], end = bktbase[blockIdx.x + 1];
    for (int j = base + t; j < end; j += 512) atomicAdd(&degl[binned[j] >> 23], 1);
    __syncthreads();
    int d = degl[t];
    s[t] = d;
    __syncthreads();
    for (int off = 1; off < 512; off <<= 1) {
        int u = (t >= off) ? s[t - off] : 0;
        __syncthreads();
        s[t] += u;
        __syncthreads();
    }
    rp[t] = base + s[t] - d;  // exclusive
    int i = n0 + t;
    if (i < N) {
        rowptr[i] = rp[t];
        dinv[i] = rsqrtf((float)(d + 1));  // +1 self-loop
    }
    __syncthreads();
    for (int j = base + t; j < end; j += 512) {
        unsigned v = binned[j];
        int li = v >> 23;
        int slot = rp[li] + atomicAdd(&cur[li], 1);
        csr_src[slot] = (int)(v & 0x7FFFFFu);
    }
}

// ---- layer-1 GEMM, M=2 register tiling, W broadcast from LDS -------------
// t1 = fp16( dinv[i] * (x[i] @ W1) )  [N,16]
// Thread handles nodes i0+t and i0+t+256. W row reads are wave-uniform ->
// LDS broadcast (conflict-free); x 16B/lane loads are L2-absorbed.
__global__ void gemm1(const float* __restrict__ x, const float* __restrict__ dinv,
                      const float* __restrict__ W, uint4* __restrict__ t1, int N) {
    __shared__ float Wl[128 * 16];  // 8 KB
    int t = threadIdx.x;
    for (int k = t; k < 128 * 16; k += 256) Wl[k] = W[k];
    __syncthreads();
    int iA = blockIdx.x * 512 + t;
    int iB = iA + 256;
    bool vA = iA < N, vB = iB < N;
    const float4* xA = (const float4*)(x + (size_t)iA * 128);
    const float4* xB = (const float4*)(x + (size_t)iB * 128);
    const float4* W4 = (const float4*)Wl;
    float4 aA[4], aB[4];
#pragma unroll
    for (int c = 0; c < 4; ++c) {
        aA[c] = make_float4(0.f, 0.f, 0.f, 0.f);
        aB[c] = make_float4(0.f, 0.f, 0.f, 0.f);
    }
    const float4 z4 = make_float4(0.f, 0.f, 0.f, 0.f);
#pragma unroll 4
    for (int k4 = 0; k4 < 32; ++k4) {
        float4 va = vA ? xA[k4] : z4;
        float4 vb = vB ? xB[k4] : z4;
#pragma unroll
        for (int kk = 0; kk < 4; ++kk) {
            float fa = (kk == 0) ? va.x : (kk == 1) ? va.y : (kk == 2) ? va.z : va.w;
            float fb = (kk == 0) ? vb.x : (kk == 1) ? vb.y : (kk == 2) ? vb.z : vb.w;
            const float4* Wr = W4 + (k4 * 4 + kk) * 4;  // wave-uniform -> broadcast
#pragma unroll
            for (int c = 0; c < 4; ++c) {
                float4 w = Wr[c];
                aA[c].x += fa * w.x; aA[c].y += fa * w.y;
                aA[c].z += fa * w.z; aA[c].w += fa * w.w;
                aB[c].x += fb * w.x; aB[c].y += fb * w.y;
                aB[c].z += fb * w.z; aB[c].w += fb * w.w;
            }
        }
    }
    if (vA) {
        float di = dinv[iA];
        float f[16];
#pragma unroll
        for (int c = 0; c < 4; ++c) {
            f[4 * c + 0] = di * aA[c].x; f[4 * c + 1] = di * aA[c].y;
            f[4 * c + 2] = di * aA[c].z; f[4 * c + 3] = di * aA[c].w;
        }
        t1[(size_t)iA * 2]     = f_to_h8(f);
        t1[(size_t)iA * 2 + 1] = f_to_h8(f + 8);
    }
    if (vB) {
        float di = dinv[iB];
        float f[16];
#pragma unroll
        for (int c = 0; c < 4; ++c) {
            f[4 * c + 0] = di * aB[c].x; f[4 * c + 1] = di * aB[c].y;
            f[4 * c + 2] = di * aB[c].z; f[4 * c + 3] = di * aB[c].w;
        }
        t1[(size_t)iB * 2]     = f_to_h8(f);
        t1[(size_t)iB * 2 + 1] = f_to_h8(f + 8);
    }
}

// ---- gather over fp16 [N,16] rows: 4 lanes/node --------------------------
// lane = (i, c = uint4 half, h = edge parity). Each h-lane sums edges
// j0+h, j0+h+2, ... (2-unrolled); halves merged via shfl_xor(2).
// EPI: out = fp16( di*relu(di*(self+sum) + b) ), else raw sums.
template <bool EPI>
__global__ void gather16(const int* __restrict__ rowptr, const int* __restrict__ csr_src,
                         const uint4* __restrict__ hs, const float* __restrict__ dinv,
                         const float* __restrict__ b, uint4* __restrict__ out, int N) {
    int tid = blockIdx.x * 256 + threadIdx.x;
    int i = tid >> 2, c = (tid >> 1) & 1, h = tid & 1;
    if (i >= N) return;
    float acc[8];
    if (h == 0) {
        h8_to_f(hs[(size_t)i * 2 + c], acc);  // self loop
    } else {
#pragma unroll
        for (int k = 0; k < 8; ++k) acc[k] = 0.f;
    }
    int j = rowptr[i] + h, end = rowptr[i + 1];
    for (; j + 2 < end; j += 4) {
        int s0 = csr_src[j], s1 = csr_src[j + 2];
        uint4 u0 = hs[(size_t)s0 * 2 + c];
        uint4 u1 = hs[(size_t)s1 * 2 + c];
        float v0[8], v1[8];
        h8_to_f(u0, v0);
        h8_to_f(u1, v1);
#pragma unroll
        for (int k = 0; k < 8; ++k) acc[k] += v0[k] + v1[k];
    }
    if (j < end) {
        int s0 = csr_src[j];
        float v0[8];
        h8_to_f(hs[(size_t)s0 * 2 + c], v0);
#pragma unroll
        for (int k = 0; k < 8; ++k) acc[k] += v0[k];
    }
#pragma unroll
    for (int k = 0; k < 8; ++k) acc[k] += __shfl_xor(acc[k], 2);
    if (h) return;
    if (EPI) {
        float di = dinv[i];
#pragma unroll
        for (int k = 0; k < 8; ++k) acc[k] = di * fmaxf(di * acc[k] + b[c * 8 + k], 0.f);
    }
    out[(size_t)i * 2 + c] = f_to_h8(acc);
}

// ---- layer-2: fused gather + GEMM, 2 lanes/node --------------------------
__global__ void gather_gemm2(const int* __restrict__ rowptr, const int* __restrict__ csr_src,
                             const uint4* __restrict__ p1, const float* __restrict__ dinv,
                             const float* __restrict__ W, const float* __restrict__ b,
                             uint4* __restrict__ p2a, uint4* __restrict__ p2b, int N) {
    __shared__ float Wl[16 * 32];
    __shared__ float bl[32];
    int t = threadIdx.x;
    for (int k = t; k < 16 * 32; k += 256) Wl[k] = W[k];
    if (t < 32) bl[t] = b[t];
    __syncthreads();
    int tid = blockIdx.x * 256 + t;
    int i = tid >> 1, h = tid & 1;
    if (i >= N) return;
    float f[16];
    if (h == 0) {
        h8_to_f(p1[(size_t)i * 2], f);
        h8_to_f(p1[(size_t)i * 2 + 1], f + 8);
    } else {
#pragma unroll
        for (int k = 0; k < 16; ++k) f[k] = 0.f;
    }
    int j = rowptr[i] + h, end = rowptr[i + 1];
    for (; j + 2 < end; j += 4) {
        int s0 = csr_src[j], s1 = csr_src[j + 2];
        uint4 a0 = p1[(size_t)s0 * 2], a1 = p1[(size_t)s0 * 2 + 1];
        uint4 b0 = p1[(size_t)s1 * 2], b1 = p1[(size_t)s1 * 2 + 1];
        float v[16], u[16];
        h8_to_f(a0, v); h8_to_f(a1, v + 8);
        h8_to_f(b0, u); h8_to_f(b1, u + 8);
#pragma unroll
        for (int k = 0; k < 16; ++k) f[k] += v[k] + u[k];
    }
    if (j < end) {
        int s0 = csr_src[j];
        float v[16];
        h8_to_f(p1[(size_t)s0 * 2], v);
        h8_to_f(p1[(size_t)s0 * 2 + 1], v + 8);
#pragma unroll
        for (int k = 0; k < 16; ++k) f[k] += v[k];
    }
#pragma unroll
    for (int k = 0; k < 16; ++k) f[k] += __shfl_xor(f[k], 1);
    const float4* W4 = (const float4*)Wl;
    float4 a[4];
#pragma unroll
    for (int c = 0; c < 4; ++c) a[c] = make_float4(0.f, 0.f, 0.f, 0.f);
#pragma unroll
    for (int k = 0; k < 16; ++k) {
        float xk = f[k];
        const float4* Wr = W4 + k * 8 + h * 4;
#pragma unroll
        for (int c = 0; c < 4; ++c) {
            float4 w = Wr[c];
            a[c].x += xk * w.x; a[c].y += xk * w.y;
            a[c].z += xk * w.z; a[c].w += xk * w.w;
        }
    }
    float di = dinv[i];
    float o[16];
#pragma unroll
    for (int c = 0; c < 4; ++c) {
        o[4 * c + 0] = di * fmaxf(di * a[c].x + bl[h * 16 + 4 * c + 0], 0.f);
        o[4 * c + 1] = di * fmaxf(di * a[c].y + bl[h * 16 + 4 * c + 1], 0.f);
        o[4 * c + 2] = di * fmaxf(di * a[c].z + bl[h * 16 + 4 * c + 2], 0.f);
        o[4 * c + 3] = di * fmaxf(di * a[c].w + bl[h * 16 + 4 * c + 3], 0.f);
    }
    uint4* dst = h ? p2b : p2a;
    dst[(size_t)i * 2]     = f_to_h8(o);
    dst[(size_t)i * 2 + 1] = f_to_h8(o + 8);
}

// ---- layer-3 GEMM fused with segment-max pool ----------------------------
__global__ void gemm3_pool(const uint4* __restrict__ g3a, const uint4* __restrict__ g3b,
                           const float* __restrict__ dinv, const float* __restrict__ W,
                           const float* __restrict__ b, const int* __restrict__ batch,
                           unsigned* __restrict__ pooled, int N) {
    __shared__ float Wl[32 * 64];
    __shared__ float bl[64];
    __shared__ float pl[128][65];
    __shared__ int bt[128];
    int t = threadIdx.x;
    for (int k = t; k < 32 * 64; k += 256) Wl[k] = W[k];
    if (t < 64) bl[t] = b[t];
    int i0 = blockIdx.x * 128;
    if (t < 128) {
        int i = i0 + t;
        bt[t] = (i < N) ? batch[i] : -1;
    }
    __syncthreads();
    int il = t & 127, c = t >> 7;  // node-local, col-half (wave-uniform)
    int i = i0 + il;
    if (i < N) {
        float f[32];
        h8_to_f(g3a[(size_t)i * 2], f);
        h8_to_f(g3a[(size_t)i * 2 + 1], f + 8);
        h8_to_f(g3b[(size_t)i * 2], f + 16);
        h8_to_f(g3b[(size_t)i * 2 + 1], f + 24);
        const float4* W4 = (const float4*)Wl;
        float4 a[8];
#pragma unroll
        for (int cc = 0; cc < 8; ++cc) a[cc] = make_float4(0.f, 0.f, 0.f, 0.f);
#pragma unroll 4
        for (int k = 0; k < 32; ++k) {
            float xk = f[k];
            const float4* Wr = W4 + k * 16 + c * 8;
#pragma unroll
            for (int cc = 0; cc < 8; ++cc) {
                float4 w = Wr[cc];
                a[cc].x += xk * w.x; a[cc].y += xk * w.y;
                a[cc].z += xk * w.z; a[cc].w += xk * w.w;
            }
        }
        float di = dinv[i];
        int fb = c * 32;
#pragma unroll
        for (int cc = 0; cc < 8; ++cc) {
            pl[il][fb + 4 * cc + 0] = fmaxf(di * a[cc].x + bl[fb + 4 * cc + 0], 0.f);
            pl[il][fb + 4 * cc + 1] = fmaxf(di * a[cc].y + bl[fb + 4 * cc + 1], 0.f);
            pl[il][fb + 4 * cc + 2] = fmaxf(di * a[cc].z + bl[fb + 4 * cc + 2], 0.f);
            pl[il][fb + 4 * cc + 3] = fmaxf(di * a[cc].w + bl[fb + 4 * cc + 3], 0.f);
        }
    }
    __syncthreads();
    // pool: 4 strips of 32 nodes, 64 features each (batch sorted)
    int f = t & 63, q = t >> 6;
    int prevb = -1;
    float run = 0.f;
    for (int k = 0; k < 32; ++k) {
        int il2 = q * 32 + k;
        int bg = bt[il2];
        if (bg < 0) break;
        float v = pl[il2][f];
        if (bg != prevb) {
            if (prevb >= 0) atomicMax(&pooled[prevb * 64 + f], __float_as_uint(run));
            prevb = bg;
            run = v;
        } else {
            run = fmaxf(run, v);
        }
    }
    if (prevb >= 0) atomicMax(&pooled[prevb * 64 + f], __float_as_uint(run));
}

// ---- MLP head: 4 graphs per block (w1/w2 reads amortized 4x) -------------
__global__ void head4(const float* __restrict__ pooled, const float* __restrict__ w1,
                      const float* __restrict__ bb1, const float* __restrict__ w2,
                      const float* __restrict__ bb2, float* __restrict__ out) {
    __shared__ float p[4][64];
    __shared__ float z[4][256];
    int g0 = blockIdx.x * 4, t = threadIdx.x;
    p[t >> 6][t & 63] = pooled[(g0 + (t >> 6)) * 64 + (t & 63)];
    __syncthreads();
    float s[4];
#pragma unroll
    for (int q = 0; q < 4; ++q) s[q] = bb1[t];
    for (int k = 0; k < 64; ++k) {
        float w = w1[k * 256 + t];
#pragma unroll
        for (int q = 0; q < 4; ++q) s[q] += p[q][k] * w;
    }
#pragma unroll
    for (int q = 0; q < 4; ++q) z[q][t] = fmaxf(s[q], 0.f);
    __syncthreads();
    float s2[4];
#pragma unroll
    for (int q = 0; q < 4; ++q) s2[q] = bb2[t];
#pragma unroll 4
    for (int k = 0; k < 256; ++k) {
        float w = w2[k * 256 + t];
#pragma unroll
        for (int q = 0; q < 4; ++q) s2[q] += z[q][k] * w;
    }
#pragma unroll
    for (int q = 0; q < 4; ++q) out[(g0 + q) * 256 + t] = 1.f / (1.f + expf(-s2[q]));
}

extern "C" void kernel_launch(void* const* d_in, const int* in_sizes, int n_in,
                              void* d_out, int out_size, void* d_ws, size_t ws_size,
                              hipStream_t stream) {
    const float* x   = (const float*)d_in[0];
    const int* ei    = (const int*)d_in[1];
    const int* batch = (const int*)d_in[2];
    const float* W1  = (const float*)d_in[3];
    const float* b1  = (const float*)d_in[4];
    const float* W2  = (const float*)d_in[5];
    const float* b2  = (const float*)d_in[6];
    const float* W3  = (const float*)d_in[7];
    const float* b3  = (const float*)d_in[8];
    const float* L1w = (const float*)d_in[9];
    const float* L1b = (const float*)d_in[10];
    const float* L2w = (const float*)d_in[11];
    const float* L2b = (const float*)d_in[12];

    const int N = in_sizes[0] / 128;
    const int E = in_sizes[1] / 2;
    const int* srcp = ei;
    const int* dstp = ei + E;
    const int NBKT = cdiv_i(N, 512);  // <= 256

    // workspace carve, 16B-aligned chunks
    char* w = (char*)d_ws;
    auto carve = [&](size_t bytes) { char* p = w; w += (bytes + 15) & ~(size_t)15; return p; };
    int*   bcnt    = (int*)carve(256 * 4);
    int*   bktbase = (int*)carve(257 * 4);
    int*   bktcur  = (int*)carve(256 * 4);
    int*   rowptr  = (int*)carve((size_t)(N + 1) * 4);
    int*   csr_src = (int*)carve((size_t)E * 4);
    float* dinv    = (float*)carve((size_t)N * 4);
    uint4* t1      = (uint4*)carve((size_t)N * 32);   // [N,16] fp16
    uint4* p1      = (uint4*)carve((size_t)N * 32);
    uint4* p2a     = (uint4*)carve((size_t)N * 32);
    uint4* p2b     = (uint4*)carve((size_t)N * 32);
    uint4* g3a     = (uint4*)carve((size_t)N * 32);
    uint4* g3b     = (uint4*)carve((size_t)N * 32);
    unsigned* binned = (unsigned*)carve((size_t)E * 4);
    unsigned* pooled = (unsigned*)carve((size_t)NG * 64 * 4);

    zero_init<<<cdiv_i(NG * 64, 256), 256, 0, stream>>>(bcnt, pooled);

    bucket_count<<<cdiv_i(E, EPB), 256, 0, stream>>>(dstp, bcnt, E);
    bucket_scan<<<1, 256, 0, stream>>>(bcnt, bktbase, bktcur, rowptr, NBKT, N);
    bin_edges<<<cdiv_i(E, EPB_BIN), 256, 0, stream>>>(srcp, dstp, bktcur, binned, E);
    bucket_build<<<NBKT, 512, 0, stream>>>(bktbase, binned, rowptr, dinv, csr_src, N);

    const int GG4 = cdiv_i((long long)N * 4, 256);  // 4-lane gather grid

    // Layer 1: t1 = fp16(dinv*(x@W1)); p1 = fp16(di*relu(di*gather(t1)+b1))
    gemm1<<<cdiv_i(N, 512), 256, 0, stream>>>(x, dinv, W1, t1, N);
    gather16<true><<<GG4, 256, 0, stream>>>(rowptr, csr_src, t1, dinv, b1, p1, N);

    // Layer 2: fused gather+GEMM (2 lanes/node) -> p2a/p2b (fp16, col-split)
    gather_gemm2<<<cdiv_i((long long)N * 2, 256), 256, 0, stream>>>(
        rowptr, csr_src, p1, dinv, W2, b2, p2a, p2b, N);

    // Layer 3 (aggregate-first, column-split, one L2-sized stream per pass)
    gather16<false><<<GG4, 256, 0, stream>>>(rowptr, csr_src, p2a, nullptr, nullptr, g3a, N);
    gather16<false><<<GG4, 256, 0, stream>>>(rowptr, csr_src, p2b, nullptr, nullptr, g3b, N);
    gemm3_pool<<<cdiv_i(N, 128), 256, 0, stream>>>(g3a, g3b, dinv, W3, b3, batch, pooled, N);

    // head: 4 graphs per block
    head4<<<NG / 4, 256, 0, stream>>>((const float*)pooled, L1w, L1b, L2w, L2b, (float*)d_out);
}

// Round 14
// 190.787 us; speedup vs baseline: 1.7139x; 1.7139x over previous
//
#include <hip/hip_runtime.h>
#include <hip/hip_fp16.h>
#include <math.h>

#define NG 1024      // NUM_GRAPHS
#define EPB 2048     // edges per bucket_count block
#define EPB_BIN 4096 // edges per bin_edges block (LDS-staged)

static inline int cdiv_i(long long a, int b) { return (int)((a + b - 1) / b); }

// ---- fp16 pack/unpack helpers (8 halves per uint4) -----------------------
union H8 { uint4 u; __half2 h[4]; };

__device__ inline void h8_to_f(uint4 uu, float* f) {
    H8 v; v.u = uu;
#pragma unroll
    for (int k = 0; k < 4; ++k) {
        float2 t = __half22float2(v.h[k]);
        f[2 * k] = t.x; f[2 * k + 1] = t.y;
    }
}
__device__ inline uint4 f_to_h8(const float* f) {
    H8 v;
#pragma unroll
    for (int k = 0; k < 4; ++k) v.h[k] = __floats2half2_rn(f[2 * k], f[2 * k + 1]);
    return v.u;
}

// ---- init: zero bcnt (256) + pooled (NG*64) in one dispatch --------------
__global__ void zero_init(int* __restrict__ bcnt, unsigned* __restrict__ pooled) {
    int t = blockIdx.x * 256 + threadIdx.x;
    if (t < 256) bcnt[t] = 0;
    if (t < NG * 64) pooled[t] = 0;
}

// ---- CSR build (bucketed) ------------------------------------------------
// bucket b = nodes [b*512, (b+1)*512)

__global__ void bucket_count(const int* __restrict__ dst, int* __restrict__ bcnt, int E) {
    __shared__ int h[256];
    int t = threadIdx.x;
    h[t] = 0;
    __syncthreads();
    int e0 = blockIdx.x * EPB;
#pragma unroll 4
    for (int k = 0; k < EPB / 256; ++k) {
        int e = e0 + k * 256 + t;
        if (e < E) atomicAdd(&h[dst[e] >> 9], 1);
    }
    __syncthreads();
    if (h[t] > 0) atomicAdd(&bcnt[t], h[t]);
}

__global__ void bucket_scan(const int* __restrict__ bcnt, int* __restrict__ bktbase,
                            int* __restrict__ bktcur, int* __restrict__ rowptr,
                            int NBKT, int N) {
    __shared__ int s[256];
    int t = threadIdx.x;
    int v = (t < NBKT) ? bcnt[t] : 0;
    s[t] = v;
    __syncthreads();
    for (int off = 1; off < 256; off <<= 1) {
        int u = (t >= off) ? s[t - off] : 0;
        __syncthreads();
        s[t] += u;
        __syncthreads();
    }
    int excl = s[t] - v;
    if (t < NBKT) { bktbase[t] = excl; bktcur[t] = excl; }
    if (t == 255) { bktbase[NBKT] = s[255]; rowptr[N] = s[255]; }
}

// bin edges bucket-major via LDS counting sort; packed = (dst&511)<<23 | src.
__global__ void bin_edges(const int* __restrict__ src, const int* __restrict__ dst,
                          int* __restrict__ bktcur, unsigned* __restrict__ binned, int E) {
    __shared__ int hist[256];
    __shared__ int sc[256];
    __shared__ int lofs[256];
    __shared__ int gbase[256];
    __shared__ int lcur[256];
    __shared__ unsigned stage[EPB_BIN];
    __shared__ int gaddr[EPB_BIN];
    int t = threadIdx.x;
    hist[t] = 0;
    __syncthreads();
    int e0 = blockIdx.x * EPB_BIN;
    int ne = E - e0; if (ne > EPB_BIN) ne = EPB_BIN;
    int myd[EPB_BIN / 256];
    int mys[EPB_BIN / 256];
#pragma unroll
    for (int k = 0; k < EPB_BIN / 256; ++k) {
        int e = e0 + k * 256 + t;
        if (e < E) {
            int d = dst[e];
            myd[k] = d;
            atomicAdd(&hist[d >> 9], 1);
        } else {
            myd[k] = -1;
        }
    }
#pragma unroll
    for (int k = 0; k < EPB_BIN / 256; ++k) {
        int e = e0 + k * 256 + t;
        mys[k] = (e < E) ? src[e] : 0;
    }
    __syncthreads();
    int v = hist[t];
    sc[t] = v;
    __syncthreads();
    for (int off = 1; off < 256; off <<= 1) {
        int u = (t >= off) ? sc[t - off] : 0;
        __syncthreads();
        sc[t] += u;
        __syncthreads();
    }
    lofs[t] = sc[t] - v;
    lcur[t] = sc[t] - v;
    if (v > 0) gbase[t] = atomicAdd(&bktcur[t], v);
    __syncthreads();
#pragma unroll
    for (int k = 0; k < EPB_BIN / 256; ++k) {
        int d = myd[k];
        if (d >= 0) {
            int b = d >> 9;
            int r = atomicAdd(&lcur[b], 1);
            stage[r] = ((unsigned)(d & 511) << 23) | (unsigned)mys[k];
            gaddr[r] = gbase[b] + (r - lofs[b]);
        }
    }
    __syncthreads();
    for (int j = t; j < ne; j += 256) binned[gaddr[j]] = stage[j];
}

__global__ void bucket_build(const int* __restrict__ bktbase, const unsigned* __restrict__ binned,
                             int* __restrict__ rowptr, float* __restrict__ dinv,
                             int* __restrict__ csr_src, int N) {
    __shared__ int degl[512];
    __shared__ int s[512];
    __shared__ int rp[512];
    __shared__ int cur[512];
    int t = threadIdx.x;  // 512
    int n0 = blockIdx.x << 9;
    degl[t] = 0;
    cur[t] = 0;
    __syncthreads();
    int base = bktbase[blockIdx.x], end = bktbase[blockIdx.x + 1];
    for (int j = base + t; j < end; j += 512) atomicAdd(&degl[binned[j] >> 23], 1);
    __syncthreads();
    int d = degl[t];
    s[t] = d;
    __syncthreads();
    for (int off = 1; off < 512; off <<= 1) {
        int u = (t >= off) ? s[t - off] : 0;
        __syncthreads();
        s[t] += u;
        __syncthreads();
    }
    rp[t] = base + s[t] - d;  // exclusive
    int i = n0 + t;
    if (i < N) {
        rowptr[i] = rp[t];
        dinv[i] = rsqrtf((float)(d + 1));  // +1 self-loop
    }
    __syncthreads();
    for (int j = base + t; j < end; j += 512) {
        unsigned v = binned[j];
        int li = v >> 23;
        int slot = rp[li] + atomicAdd(&cur[li], 1);
        csr_src[slot] = (int)(v & 0x7FFFFFu);
    }
}

// ---- layer-1 GEMM (proven simple): t1 = fp16( dinv[i]*(x[i]@W1) ) [N,16] --
// One node/thread, W in LDS (8 KB), float4 x reads, a[4] accumulators.
// Register demand fits (no spill) — do NOT add M-tiling here (round-12 spill).
__global__ void gemm1(const float* __restrict__ x, const float* __restrict__ dinv,
                      const float* __restrict__ W, uint4* __restrict__ t1, int N) {
    __shared__ float Wl[128 * 16];
    int t = threadIdx.x;
    for (int k = t; k < 128 * 16; k += 256) Wl[k] = W[k];
    __syncthreads();
    int i = blockIdx.x * 256 + t;
    if (i >= N) return;
    const float4* x4 = (const float4*)(x + (size_t)i * 128);
    const float4* W4 = (const float4*)Wl;
    float4 a[4];
#pragma unroll
    for (int c = 0; c < 4; ++c) a[c] = make_float4(0.f, 0.f, 0.f, 0.f);
#pragma unroll 4
    for (int k4 = 0; k4 < 32; ++k4) {
        float4 v = x4[k4];
#pragma unroll
        for (int kk = 0; kk < 4; ++kk) {
            float xk = (kk == 0) ? v.x : (kk == 1) ? v.y : (kk == 2) ? v.z : v.w;
            const float4* Wr = W4 + (k4 * 4 + kk) * 4;
#pragma unroll
            for (int c = 0; c < 4; ++c) {
                float4 w = Wr[c];
                a[c].x += xk * w.x; a[c].y += xk * w.y;
                a[c].z += xk * w.z; a[c].w += xk * w.w;
            }
        }
    }
    float di = dinv[i];
    float f[16];
#pragma unroll
    for (int c = 0; c < 4; ++c) {
        f[4 * c + 0] = di * a[c].x; f[4 * c + 1] = di * a[c].y;
        f[4 * c + 2] = di * a[c].z; f[4 * c + 3] = di * a[c].w;
    }
    t1[(size_t)i * 2]     = f_to_h8(f);
    t1[(size_t)i * 2 + 1] = f_to_h8(f + 8);
}

// ---- gather over fp16 [N,16] rows: 4 lanes/node --------------------------
// lane = (i, c = uint4 half, h = edge parity). Each h-lane sums edges
// j0+h, j0+h+2, ... (2-unrolled); halves merged via shfl_xor(2).
// EPI: out = fp16( di*relu(di*(self+sum) + b) ), else raw sums.
template <bool EPI>
__global__ void gather16(const int* __restrict__ rowptr, const int* __restrict__ csr_src,
                         const uint4* __restrict__ hs, const float* __restrict__ dinv,
                         const float* __restrict__ b, uint4* __restrict__ out, int N) {
    int tid = blockIdx.x * 256 + threadIdx.x;
    int i = tid >> 2, c = (tid >> 1) & 1, h = tid & 1;
    if (i >= N) return;
    float acc[8];
    if (h == 0) {
        h8_to_f(hs[(size_t)i * 2 + c], acc);  // self loop
    } else {
#pragma unroll
        for (int k = 0; k < 8; ++k) acc[k] = 0.f;
    }
    int j = rowptr[i] + h, end = rowptr[i + 1];
    for (; j + 2 < end; j += 4) {
        int s0 = csr_src[j], s1 = csr_src[j + 2];
        uint4 u0 = hs[(size_t)s0 * 2 + c];
        uint4 u1 = hs[(size_t)s1 * 2 + c];
        float v0[8], v1[8];
        h8_to_f(u0, v0);
        h8_to_f(u1, v1);
#pragma unroll
        for (int k = 0; k < 8; ++k) acc[k] += v0[k] + v1[k];
    }
    if (j < end) {
        int s0 = csr_src[j];
        float v0[8];
        h8_to_f(hs[(size_t)s0 * 2 + c], v0);
#pragma unroll
        for (int k = 0; k < 8; ++k) acc[k] += v0[k];
    }
#pragma unroll
    for (int k = 0; k < 8; ++k) acc[k] += __shfl_xor(acc[k], 2);
    if (h) return;
    if (EPI) {
        float di = dinv[i];
#pragma unroll
        for (int k = 0; k < 8; ++k) acc[k] = di * fmaxf(di * acc[k] + b[c * 8 + k], 0.f);
    }
    out[(size_t)i * 2 + c] = f_to_h8(acc);
}

// ---- layer-2: fused gather + GEMM, 2 lanes/node --------------------------
__global__ void gather_gemm2(const int* __restrict__ rowptr, const int* __restrict__ csr_src,
                             const uint4* __restrict__ p1, const float* __restrict__ dinv,
                             const float* __restrict__ W, const float* __restrict__ b,
                             uint4* __restrict__ p2a, uint4* __restrict__ p2b, int N) {
    __shared__ float Wl[16 * 32];
    __shared__ float bl[32];
    int t = threadIdx.x;
    for (int k = t; k < 16 * 32; k += 256) Wl[k] = W[k];
    if (t < 32) bl[t] = b[t];
    __syncthreads();
    int tid = blockIdx.x * 256 + t;
    int i = tid >> 1, h = tid & 1;
    if (i >= N) return;
    float f[16];
    if (h == 0) {
        h8_to_f(p1[(size_t)i * 2], f);
        h8_to_f(p1[(size_t)i * 2 + 1], f + 8);
    } else {
#pragma unroll
        for (int k = 0; k < 16; ++k) f[k] = 0.f;
    }
    int j = rowptr[i] + h, end = rowptr[i + 1];
    for (; j + 2 < end; j += 4) {
        int s0 = csr_src[j], s1 = csr_src[j + 2];
        uint4 a0 = p1[(size_t)s0 * 2], a1 = p1[(size_t)s0 * 2 + 1];
        uint4 b0 = p1[(size_t)s1 * 2], b1 = p1[(size_t)s1 * 2 + 1];
        float v[16], u[16];
        h8_to_f(a0, v); h8_to_f(a1, v + 8);
        h8_to_f(b0, u); h8_to_f(b1, u + 8);
#pragma unroll
        for (int k = 0; k < 16; ++k) f[k] += v[k] + u[k];
    }
    if (j < end) {
        int s0 = csr_src[j];
        float v[16];
        h8_to_f(p1[(size_t)s0 * 2], v);
        h8_to_f(p1[(size_t)s0 * 2 + 1], v + 8);
#pragma unroll
        for (int k = 0; k < 16; ++k) f[k] += v[k];
    }
#pragma unroll
    for (int k = 0; k < 16; ++k) f[k] += __shfl_xor(f[k], 1);
    const float4* W4 = (const float4*)Wl;
    float4 a[4];
#pragma unroll
    for (int c = 0; c < 4; ++c) a[c] = make_float4(0.f, 0.f, 0.f, 0.f);
#pragma unroll
    for (int k = 0; k < 16; ++k) {
        float xk = f[k];
        const float4* Wr = W4 + k * 8 + h * 4;
#pragma unroll
        for (int c = 0; c < 4; ++c) {
            float4 w = Wr[c];
            a[c].x += xk * w.x; a[c].y += xk * w.y;
            a[c].z += xk * w.z; a[c].w += xk * w.w;
        }
    }
    float di = dinv[i];
    float o[16];
#pragma unroll
    for (int c = 0; c < 4; ++c) {
        o[4 * c + 0] = di * fmaxf(di * a[c].x + bl[h * 16 + 4 * c + 0], 0.f);
        o[4 * c + 1] = di * fmaxf(di * a[c].y + bl[h * 16 + 4 * c + 1], 0.f);
        o[4 * c + 2] = di * fmaxf(di * a[c].z + bl[h * 16 + 4 * c + 2], 0.f);
        o[4 * c + 3] = di * fmaxf(di * a[c].w + bl[h * 16 + 4 * c + 3], 0.f);
    }
    uint4* dst = h ? p2b : p2a;
    dst[(size_t)i * 2]     = f_to_h8(o);
    dst[(size_t)i * 2 + 1] = f_to_h8(o + 8);
}

// ---- layer-3 GEMM fused with segment-max pool ----------------------------
__global__ void gemm3_pool(const uint4* __restrict__ g3a, const uint4* __restrict__ g3b,
                           const float* __restrict__ dinv, const float* __restrict__ W,
                           const float* __restrict__ b, const int* __restrict__ batch,
                           unsigned* __restrict__ pooled, int N) {
    __shared__ float Wl[32 * 64];
    __shared__ float bl[64];
    __shared__ float pl[128][65];
    __shared__ int bt[128];
    int t = threadIdx.x;
    for (int k = t; k < 32 * 64; k += 256) Wl[k] = W[k];
    if (t < 64) bl[t] = b[t];
    int i0 = blockIdx.x * 128;
    if (t < 128) {
        int i = i0 + t;
        bt[t] = (i < N) ? batch[i] : -1;
    }
    __syncthreads();
    int il = t & 127, c = t >> 7;  // node-local, col-half (wave-uniform)
    int i = i0 + il;
    if (i < N) {
        float f[32];
        h8_to_f(g3a[(size_t)i * 2], f);
        h8_to_f(g3a[(size_t)i * 2 + 1], f + 8);
        h8_to_f(g3b[(size_t)i * 2], f + 16);
        h8_to_f(g3b[(size_t)i * 2 + 1], f + 24);
        const float4* W4 = (const float4*)Wl;
        float4 a[8];
#pragma unroll
        for (int cc = 0; cc < 8; ++cc) a[cc] = make_float4(0.f, 0.f, 0.f, 0.f);
#pragma unroll 4
        for (int k = 0; k < 32; ++k) {
            float xk = f[k];
            const float4* Wr = W4 + k * 16 + c * 8;
#pragma unroll
            for (int cc = 0; cc < 8; ++cc) {
                float4 w = Wr[cc];
                a[cc].x += xk * w.x; a[cc].y += xk * w.y;
                a[cc].z += xk * w.z; a[cc].w += xk * w.w;
            }
        }
        float di = dinv[i];
        int fb = c * 32;
#pragma unroll
        for (int cc = 0; cc < 8; ++cc) {
            pl[il][fb + 4 * cc + 0] = fmaxf(di * a[cc].x + bl[fb + 4 * cc + 0], 0.f);
            pl[il][fb + 4 * cc + 1] = fmaxf(di * a[cc].y + bl[fb + 4 * cc + 1], 0.f);
            pl[il][fb + 4 * cc + 2] = fmaxf(di * a[cc].z + bl[fb + 4 * cc + 2], 0.f);
            pl[il][fb + 4 * cc + 3] = fmaxf(di * a[cc].w + bl[fb + 4 * cc + 3], 0.f);
        }
    }
    __syncthreads();
    // pool: 4 strips of 32 nodes, 64 features each (batch sorted)
    int f = t & 63, q = t >> 6;
    int prevb = -1;
    float run = 0.f;
    for (int k = 0; k < 32; ++k) {
        int il2 = q * 32 + k;
        int bg = bt[il2];
        if (bg < 0) break;
        float v = pl[il2][f];
        if (bg != prevb) {
            if (prevb >= 0) atomicMax(&pooled[prevb * 64 + f], __float_as_uint(run));
            prevb = bg;
            run = v;
        } else {
            run = fmaxf(run, v);
        }
    }
    if (prevb >= 0) atomicMax(&pooled[prevb * 64 + f], __float_as_uint(run));
}

// ---- MLP head: 4 graphs per block (w1/w2 reads amortized 4x) -------------
__global__ void head4(const float* __restrict__ pooled, const float* __restrict__ w1,
                      const float* __restrict__ bb1, const float* __restrict__ w2,
                      const float* __restrict__ bb2, float* __restrict__ out) {
    __shared__ float p[4][64];
    __shared__ float z[4][256];
    int g0 = blockIdx.x * 4, t = threadIdx.x;
    p[t >> 6][t & 63] = pooled[(g0 + (t >> 6)) * 64 + (t & 63)];
    __syncthreads();
    float s[4];
#pragma unroll
    for (int q = 0; q < 4; ++q) s[q] = bb1[t];
    for (int k = 0; k < 64; ++k) {
        float w = w1[k * 256 + t];
#pragma unroll
        for (int q = 0; q < 4; ++q) s[q] += p[q][k] * w;
    }
#pragma unroll
    for (int q = 0; q < 4; ++q) z[q][t] = fmaxf(s[q], 0.f);
    __syncthreads();
    float s2[4];
#pragma unroll
    for (int q = 0; q < 4; ++q) s2[q] = bb2[t];
#pragma unroll 4
    for (int k = 0; k < 256; ++k) {
        float w = w2[k * 256 + t];
#pragma unroll
        for (int q = 0; q < 4; ++q) s2[q] += z[q][k] * w;
    }
#pragma unroll
    for (int q = 0; q < 4; ++q) out[(g0 + q) * 256 + t] = 1.f / (1.f + expf(-s2[q]));
}

extern "C" void kernel_launch(void* const* d_in, const int* in_sizes, int n_in,
                              void* d_out, int out_size, void* d_ws, size_t ws_size,
                              hipStream_t stream) {
    const float* x   = (const float*)d_in[0];
    const int* ei    = (const int*)d_in[1];
    const int* batch = (const int*)d_in[2];
    const float* W1  = (const float*)d_in[3];
    const float* b1  = (const float*)d_in[4];
    const float* W2  = (const float*)d_in[5];
    const float* b2  = (const float*)d_in[6];
    const float* W3  = (const float*)d_in[7];
    const float* b3  = (const float*)d_in[8];
    const float* L1w = (const float*)d_in[9];
    const float* L1b = (const float*)d_in[10];
    const float* L2w = (const float*)d_in[11];
    const float* L2b = (const float*)d_in[12];

    const int N = in_sizes[0] / 128;
    const int E = in_sizes[1] / 2;
    const int* srcp = ei;
    const int* dstp = ei + E;
    const int NB = cdiv_i(N, 256);
    const int NBKT = cdiv_i(N, 512);  // <= 256

    // workspace carve, 16B-aligned chunks
    char* w = (char*)d_ws;
    auto carve = [&](size_t bytes) { char* p = w; w += (bytes + 15) & ~(size_t)15; return p; };
    int*   bcnt    = (int*)carve(256 * 4);
    int*   bktbase = (int*)carve(257 * 4);
    int*   bktcur  = (int*)carve(256 * 4);
    int*   rowptr  = (int*)carve((size_t)(N + 1) * 4);
    int*   csr_src = (int*)carve((size_t)E * 4);
    float* dinv    = (float*)carve((size_t)N * 4);
    uint4* t1      = (uint4*)carve((size_t)N * 32);   // [N,16] fp16
    uint4* p1      = (uint4*)carve((size_t)N * 32);
    uint4* p2a     = (uint4*)carve((size_t)N * 32);
    uint4* p2b     = (uint4*)carve((size_t)N * 32);
    uint4* g3a     = (uint4*)carve((size_t)N * 32);
    uint4* g3b     = (uint4*)carve((size_t)N * 32);
    unsigned* binned = (unsigned*)carve((size_t)E * 4);
    unsigned* pooled = (unsigned*)carve((size_t)NG * 64 * 4);

    zero_init<<<cdiv_i(NG * 64, 256), 256, 0, stream>>>(bcnt, pooled);

    bucket_count<<<cdiv_i(E, EPB), 256, 0, stream>>>(dstp, bcnt, E);
    bucket_scan<<<1, 256, 0, stream>>>(bcnt, bktbase, bktcur, rowptr, NBKT, N);
    bin_edges<<<cdiv_i(E, EPB_BIN), 256, 0, stream>>>(srcp, dstp, bktcur, binned, E);
    bucket_build<<<NBKT, 512, 0, stream>>>(bktbase, binned, rowptr, dinv, csr_src, N);

    const int GG4 = cdiv_i((long long)N * 4, 256);  // 4-lane gather grid

    // Layer 1: t1 = fp16(dinv*(x@W1)); p1 = fp16(di*relu(di*gather(t1)+b1))
    gemm1<<<NB, 256, 0, stream>>>(x, dinv, W1, t1, N);
    gather16<true><<<GG4, 256, 0, stream>>>(rowptr, csr_src, t1, dinv, b1, p1, N);

    // Layer 2: fused gather+GEMM (2 lanes/node) -> p2a/p2b (fp16, col-split)
    gather_gemm2<<<cdiv_i((long long)N * 2, 256), 256, 0, stream>>>(
        rowptr, csr_src, p1, dinv, W2, b2, p2a, p2b, N);

    // Layer 3 (aggregate-first, column-split, one L2-sized stream per pass)
    gather16<false><<<GG4, 256, 0, stream>>>(rowptr, csr_src, p2a, nullptr, nullptr, g3a, N);
    gather16<false><<<GG4, 256, 0, stream>>>(rowptr, csr_src, p2b, nullptr, nullptr, g3b, N);
    gemm3_pool<<<cdiv_i(N, 128), 256, 0, stream>>>(g3a, g3b, dinv, W3, b3, batch, pooled, N);

    // head: 4 graphs per block
    head4<<<NG / 4, 256, 0, stream>>>((const float*)pooled, L1w, L1b, L2w, L2b, (float*)d_out);
}